// Round 1
// 198.423 us; speedup vs baseline: 1.0141x; 1.0141x over previous
//
#include <hip/hip_runtime.h>

// Problem constants (B, C, K, H, W) = (32, 256, 64, 56, 56)
constexpr int BB   = 32;
constexpr int CC   = 256;
constexpr int HWN  = 56 * 56;                       // 3136 floats per plane
constexpr int PL4  = HWN / 4;                       // 784 float4 per plane
constexpr int N4   = BB * CC * PL4;                 // 6,422,528 float4 total
constexpr int GRID = 3136;                          // 3136 blk * 256 thr * 8 f4 = N4 exactly
constexpr int TT   = GRID * 256;                    // total threads = 802,816 float4 per stride step

// Key invariant: TT / PL4 = 1024 exactly (784 * 1024 = 802,816). Stepping j by TT
// advances exactly 1024 planes: channel c = plane & 255 and hw4 are INVARIANT
// across a thread's 8 accesses; only b advances (by 1024/256 = 4 per step).
// => per-thread index math / LDS lookups / branch are hoisted out of the 8x loop.

// floor(y/49) for y < 2^19 via magic multiply: 49*43826197 = 2^31 + 5.
constexpr unsigned long long MAGIC49 = 43826197ull;

typedef float v4f __attribute__((ext_vector_type(4)));

__device__ __forceinline__ float edac_pair(float x, float y, float lo, float hi) {
    if (x != x) x = 0.0f;            // nan_to_num
    if (y != y) y = 0.0f;
    bool mv = (x >= lo) && (x <= hi);
    bool dv = (y >= lo) && (y <= hi);
    return (mv && dv && (x != y)) ? fminf(x, y)
         : ((dv && !mv) ? y
         : (mv ? x : 0.0f));
}

__device__ __forceinline__ float edac_single(float x, float lo, float hi) {
    if (x != x) x = 0.0f;
    return ((x >= lo) && (x <= hi)) ? x : 0.0f;
}

__global__ __launch_bounds__(256) void edac_flat(
    const float* __restrict__ mainp,
    const float* __restrict__ dupp,
    const float* __restrict__ lov,
    const float* __restrict__ hiv,
    const int*   __restrict__ vidx,
    float*       __restrict__ out,
    int K)
{
    __shared__ float s_lo[CC];
    __shared__ float s_hi[CC];
    __shared__ int   s_inv[CC];

    const int t = threadIdx.x;
    s_lo[t]  = lov[t];
    s_hi[t]  = hiv[t];
    s_inv[t] = -1;
    __syncthreads();
    if (t < K) s_inv[vidx[t]] = t;
    __syncthreads();

    const v4f* m4 = (const v4f*)mainp;
    const v4f* d4 = (const v4f*)dupp;
    v4f*       o4 = (v4f*)out;

    const int j0 = blockIdx.x * 256 + t;

    // Per-thread invariant index math (was done 8x before).
    const unsigned y      = ((unsigned)j0) >> 4;
    const int      plane0 = (int)(((unsigned long long)y * MAGIC49) >> 31);  // j0/784
    const int      c      = plane0 & (CC - 1);
    const int      hw4    = j0 - plane0 * PL4;
    const int      b0     = plane0 >> 8;                                     // / CC

    const float lo = s_lo[c];
    const float hi = s_hi[c];
    const int   k  = s_inv[c];

    // Issue all 8 main-tensor loads up front for max memory-level parallelism.
    v4f m[8];
    #pragma unroll
    for (int u = 0; u < 8; ++u)
        m[u] = __builtin_nontemporal_load(&m4[j0 + u * TT]);

    if (k >= 0) {
        // b advances by 4 per stride step -> dup f4-index advances by 4*K*PL4.
        const size_t dbase = ((size_t)b0 * K + k) * PL4 + (size_t)hw4;
        const size_t dstep = (size_t)4 * K * PL4;
        v4f d[8];
        #pragma unroll
        for (int u = 0; u < 8; ++u)
            d[u] = __builtin_nontemporal_load(&d4[dbase + (size_t)u * dstep]);

        #pragma unroll
        for (int u = 0; u < 8; ++u) {
            v4f r;
            #pragma unroll
            for (int e = 0; e < 4; ++e)
                r[e] = edac_pair(m[u][e], d[u][e], lo, hi);
            __builtin_nontemporal_store(r, &o4[j0 + u * TT]);
        }
    } else {
        #pragma unroll
        for (int u = 0; u < 8; ++u) {
            v4f r;
            #pragma unroll
            for (int e = 0; e < 4; ++e)
                r[e] = edac_single(m[u][e], lo, hi);
            __builtin_nontemporal_store(r, &o4[j0 + u * TT]);
        }
    }
}

extern "C" void kernel_launch(void* const* d_in, const int* in_sizes, int n_in,
                              void* d_out, int out_size, void* d_ws, size_t ws_size,
                              hipStream_t stream) {
    const float* mainp = (const float*)d_in[0];
    const float* dupp  = (const float*)d_in[1];
    const float* lov   = (const float*)d_in[2];
    const float* hiv   = (const float*)d_in[3];
    const int*   vidx  = (const int*)d_in[4];
    const int    K     = in_sizes[4];

    hipLaunchKernelGGL(edac_flat, dim3(GRID), dim3(256), 0, stream,
                       mainp, dupp, lov, hiv, vidx, (float*)d_out, K);
}